// Round 1
// baseline (826.648 us; speedup 1.0000x reference)
//
#include <hip/hip_runtime.h>
#include <math.h>

#define EPSF 1e-8f
#define ATT_NORM_F 2.0f

constexpr int H = 8;
constexpr int N_NODES_C = 50000;

// Layout change vs previous version: one thread per float4 (4 lanes per [e,h]
// row of D=16 floats). Global loads are fully coalesced (wave = 1 KiB
// contiguous per instruction) instead of 64 B/lane strided, which had every
// lane of a wave on a distinct cacheline (4 KB span per instruction).
// Row norm = 4-lane butterfly reduce via __shfl_xor (no LDS).

// Pass 1: nj = ||x_j[e,h,:]|| + eps ; scatter-max into node_max[index[e]*H+h].
// node_max holds float bits as uint: all nj > 0, so uint max == float max and
// the zeroed buffer is exactly the reference's 0.0f segment-max base.
__global__ __launch_bounds__(256) void nj_scatter_max(
    const float4* __restrict__ x_j4,
    const int* __restrict__ index,
    unsigned int* __restrict__ node_max,
    int EH4)
{
    int g = blockIdx.x * 256 + threadIdx.x;
    if (g >= EH4) return;
    float4 v = x_j4[g];
    float s = fmaf(v.x, v.x, fmaf(v.y, v.y, fmaf(v.z, v.z, v.w * v.w)));
    // lanes {4k,4k+1,4k+2,4k+3} hold partial sums of row t = g>>2
    s += __shfl_xor(s, 1);
    s += __shfl_xor(s, 2);
    if ((threadIdx.x & 3) == 0) {
        int t = g >> 2;          // row id = e*H + h
        int e = t >> 3;          // t / H
        int h = t & 7;           // t % H
        unsigned int bits = __float_as_uint(sqrtf(s) + EPSF);
        unsigned int* slot = node_max + index[e] * H + h;
        // Read-filter: slot value is monotonically increasing, so a stale read
        // is <= current; skipping only when bits <= stale is always safe and
        // removes most contended RMWs (~16 candidates/slot, L2-resident).
        if (bits > *slot) atomicMax(slot, bits);
    }
}

// Pass 2: ni = ||x_i[e,h,:]|| + eps ; denom = 2*(ni + (seg_max + eps)) + eps ;
// out = clip(e_ij / denom, -10, 10)
__global__ __launch_bounds__(256) void lipschitz_out(
    const float4* __restrict__ x_i4,
    const float* __restrict__ e_ij,
    const int* __restrict__ index,
    const unsigned int* __restrict__ node_max,
    float* __restrict__ out,
    int EH4)
{
    int g = blockIdx.x * 256 + threadIdx.x;
    if (g >= EH4) return;
    float4 v = x_i4[g];
    float s = fmaf(v.x, v.x, fmaf(v.y, v.y, fmaf(v.z, v.z, v.w * v.w)));
    s += __shfl_xor(s, 1);
    s += __shfl_xor(s, 2);
    if ((threadIdx.x & 3) == 0) {
        int t = g >> 2;
        int e = t >> 3;
        int h = t & 7;
        float ni = sqrtf(s) + EPSF;
        float m = __uint_as_float(node_max[index[e] * H + h]) + EPSF;
        float denom = ATT_NORM_F * (ni + m) + EPSF;
        float r = e_ij[t] / denom;
        out[t] = fminf(10.0f, fmaxf(-10.0f, r));
    }
}

extern "C" void kernel_launch(void* const* d_in, const int* in_sizes, int n_in,
                              void* d_out, int out_size, void* d_ws, size_t ws_size,
                              hipStream_t stream)
{
    const float* e_ij  = (const float*)d_in[0];  // [E, H]
    const float* x_i   = (const float*)d_in[1];  // [E, H, D]
    const float* x_j   = (const float*)d_in[2];  // [E, H, D]
    const int*   index = (const int*)d_in[3];    // [E]

    float* out = (float*)d_out;                   // [E, H]
    unsigned int* node_max = (unsigned int*)d_ws; // [N_NODES, H] float-as-uint

    const int EH  = in_sizes[0];                  // E * H = 6.4M
    const int EH4 = EH * 4;                       // float4 count = 25.6M

    // Zero the segment-max base (ws is poisoned before every launch).
    hipMemsetAsync(node_max, 0, (size_t)N_NODES_C * H * sizeof(unsigned int), stream);

    const int block = 256;
    const int grid = (EH4 + block - 1) / block;

    nj_scatter_max<<<grid, block, 0, stream>>>(
        reinterpret_cast<const float4*>(x_j), index, node_max, EH4);
    lipschitz_out<<<grid, block, 0, stream>>>(
        reinterpret_cast<const float4*>(x_i), e_ij, index, node_max, out, EH4);
}